// Round 6
// baseline (176.792 us; speedup 1.0000x reference)
//
#include <hip/hip_runtime.h>
#include <hip/hip_bf16.h>
#include <math.h>

#define T_STEPS 65536
#define DDIM 256
#define RDIM 32
#define MDIM 52
#define CHUNK 64
#define NCH (T_STEPS / CHUNK)   // 1024 chunks
#define SCH 16                  // chunks per superchunk
#define NSC (NCH / SCH)         // 64 superchunks

typedef short short8 __attribute__((ext_vector_type(8)));   // 8 bf16 (4 VGPRs)
typedef short short4_ __attribute__((ext_vector_type(4)));  // 4 bf16 (2 VGPRs)
typedef float f32x4  __attribute__((ext_vector_type(4)));   // MFMA acc

union bf8pack { short8 v; __hip_bfloat16 h[8]; };
union bf4pack { short4_ v; __hip_bfloat16 h[4]; };

// ---------------------------------------------------------------------------
// K1: MFMA projections + phase A + intra-chunk attention. 3 kernels total in
// the pipeline now: prepB is gone — each lane packs its own B-fragment
// directly from Wk/Wv/Wq (L2-hot 96 KB, bit-identical RNE cvt to the old
// prepB path). S is stored TRANSPOSED (element e = b*32 + a) so the MFMA reg
// axis is memory-fastest -> one float4 store per lane.
// ---------------------------------------------------------------------------
__global__ __launch_bounds__(256) void projA_kernel(
    const float* __restrict__ X,
    const float* __restrict__ lr, const float* __restrict__ decay,
    const float* __restrict__ Wk, const float* __restrict__ Wv,
    const float* __restrict__ Wq,
    const float* __restrict__ bk, const float* __restrict__ bv,
    const float* __restrict__ bq,
    __hip_bfloat16* __restrict__ Qtil, __hip_bfloat16* __restrict__ Fin,
    float* __restrict__ Schunk, float* __restrict__ Pchunk)
{
    __shared__ __hip_bfloat16 kR[CHUNK][40];  // k̃ rows (scores B-frag)
    __shared__ __hip_bfloat16 qR[CHUNK][40];  // q̃ rows (A-frag + plane copy)
    __shared__ __hip_bfloat16 kT[32][72];     // k̃^T (S-MFMA A-frag)
    __shared__ __hip_bfloat16 vT[32][72];     // v^T  (S-MFMA + PV B-frag)
    __shared__ __hip_bfloat16 scb[CHUNK][72]; // masked scores

    const int tid  = threadIdx.x;
    const int wv   = tid >> 6;
    const int lane = tid & 63;
    const int l15  = lane & 15;
    const int q4   = lane >> 4;
    const int ch   = blockIdx.x;
    const int t0   = ch * CHUNK;

    // redundant per-wave decay cumprod (overlaps X-load latency; no LDS/barrier)
    float bcum = 1.f - decay[t0 + lane];
    const float lcum = lr[t0 + lane];
#pragma unroll
    for (int d = 1; d < 64; d <<= 1) {
        float o = __shfl_up(bcum, d, 64);
        if (lane >= d) bcum *= o;
    }
    const float P = __shfl(bcum, 63, 64);

    // MFMA GEMM: C[64x96] = X_tile[64x256] * W^T  — all 16 X loads hoisted
    const float* xrow = X + (size_t)(t0 + 16 * wv + l15) * DDIM + q4 * 8;
    float4 xa[16];
#pragma unroll
    for (int kb = 0; kb < 8; kb++) {
        xa[2 * kb]     = *(const float4*)(xrow + kb * 32);
        xa[2 * kb + 1] = *(const float4*)(xrow + kb * 32 + 4);
    }
    // per-lane W row pointers (B-fragment source; lane reads row 16c+l15,
    // cols kb*32 + q4*8 .. +7 — exactly the old prepB fragment layout)
    const float* wrow[6];
#pragma unroll
    for (int c = 0; c < 6; c++) {
        wrow[c] = ((c < 2) ? (Wk + (size_t)(16 * c       + l15) * DDIM)
                 : (c < 4) ? (Wv + (size_t)(16 * (c - 2) + l15) * DDIM)
                           : (Wq + (size_t)(16 * (c - 4) + l15) * DDIM)) + q4 * 8;
    }
    // bias prefetch (L1-hot; issued early, consumed after the MFMA loop)
    float biasr[6];
#pragma unroll
    for (int c = 0; c < 6; c++) {
        const int colg = 16 * c + l15;
        biasr[c] = (colg < 32) ? bk[colg]
                 : (colg < 64) ? bv[colg - 32] : bq[colg - 64];
    }
    f32x4 acc[6];
#pragma unroll
    for (int c = 0; c < 6; c++) acc[c] = (f32x4){0.f, 0.f, 0.f, 0.f};
#pragma unroll
    for (int kb = 0; kb < 8; kb++) {
        const float4 a0 = xa[2 * kb], a1 = xa[2 * kb + 1];
        bf8pack ap;
        ap.h[0] = __float2bfloat16(a0.x); ap.h[1] = __float2bfloat16(a0.y);
        ap.h[2] = __float2bfloat16(a0.z); ap.h[3] = __float2bfloat16(a0.w);
        ap.h[4] = __float2bfloat16(a1.x); ap.h[5] = __float2bfloat16(a1.y);
        ap.h[6] = __float2bfloat16(a1.z); ap.h[7] = __float2bfloat16(a1.w);
#pragma unroll
        for (int c = 0; c < 6; c++) {
            const float4 b0 = *(const float4*)(wrow[c] + kb * 32);
            const float4 b1 = *(const float4*)(wrow[c] + kb * 32 + 4);
            bf8pack bp;
            bp.h[0] = __float2bfloat16(b0.x); bp.h[1] = __float2bfloat16(b0.y);
            bp.h[2] = __float2bfloat16(b0.z); bp.h[3] = __float2bfloat16(b0.w);
            bp.h[4] = __float2bfloat16(b1.x); bp.h[5] = __float2bfloat16(b1.y);
            bp.h[6] = __float2bfloat16(b1.z); bp.h[7] = __float2bfloat16(b1.w);
            acc[c] = __builtin_amdgcn_mfma_f32_16x16x32_bf16(ap.v, bp.v, acc[c], 0, 0, 0);
        }
    }

    // per-row scales for this lane's 4 accumulator rows (sloc = 16wv+4q4+r)
    float bbr[4], llr[4];
#pragma unroll
    for (int r = 0; r < 4; r++) {
        const int sloc = 16 * wv + 4 * q4 + r;
        bbr[r] = __shfl(bcum, sloc, 64);
        llr[r] = __shfl(lcum, sloc, 64);
    }

    // scatter accumulators into bf16 LDS tiles; kT/vT rows packed as b64
    const int sbase = 16 * wv + 4 * q4;
#pragma unroll
    for (int c = 0; c < 6; c++) {
        const int colg = 16 * c + l15;
        const float bias = biasr[c];
        if (c < 2) {
            bf4pack pk;
#pragma unroll
            for (int r = 0; r < 4; r++) {
                __hip_bfloat16 h = __float2bfloat16((acc[c][r] + bias) * (llr[r] / bbr[r]));
                kR[sbase + r][colg] = h;
                pk.h[r] = h;
            }
            *(short4_*)(&kT[colg][sbase]) = pk.v;
        } else if (c < 4) {
            bf4pack pv;
#pragma unroll
            for (int r = 0; r < 4; r++)
                pv.h[r] = __float2bfloat16(acc[c][r] + bias);
            *(short4_*)(&vT[colg - 32][sbase]) = pv.v;
        } else {
#pragma unroll
            for (int r = 0; r < 4; r++)
                qR[sbase + r][colg - 64] = __float2bfloat16((acc[c][r] + bias) * bbr[r]);
        }
    }
    __syncthreads();                    // tiles ready

    // coalesced Qtil plane write
    {
        const int s = tid >> 2, g = (tid & 3) * 8;
        *(short8*)(Qtil + (size_t)(t0 + s) * 32 + g) = *(const short8*)(&qR[s][g]);
    }

    // S^T store: element e = b*32 + a (a = k-idx, b = v-idx), rr fastest
    {
        const int am = wv & 1, bn = wv >> 1;
        f32x4 sacc = (f32x4){0.f, 0.f, 0.f, 0.f};
#pragma unroll
        for (int k2 = 0; k2 < 2; k2++) {
            short8 aF = *(const short8*)(&kT[16 * am + l15][k2 * 32 + q4 * 8]);
            short8 bF = *(const short8*)(&vT[16 * bn + l15][k2 * 32 + q4 * 8]);
            sacc = __builtin_amdgcn_mfma_f32_16x16x32_bf16(aF, bF, sacc, 0, 0, 0);
        }
        f32x4 sv;
#pragma unroll
        for (int rr = 0; rr < 4; rr++) sv[rr] = P * sacc[rr];
        *(f32x4*)(Schunk + (size_t)ch * 1024
                  + (16 * bn + l15) * 32 + 16 * am + 4 * q4) = sv;
    }
    if (tid == 0) Pchunk[ch] = P;

    // scores: Q̃ K̃^T (4 MFMAs/wave), mask s<=t, bf16 -> scb
    const short8 aq = *(const short8*)(&qR[16 * wv + l15][q4 * 8]);
    f32x4 sc4[4];
#pragma unroll
    for (int sn = 0; sn < 4; sn++) {
        short8 bk8 = *(const short8*)(&kR[16 * sn + l15][q4 * 8]);
        sc4[sn] = __builtin_amdgcn_mfma_f32_16x16x32_bf16(
            aq, bk8, (f32x4){0.f, 0.f, 0.f, 0.f}, 0, 0, 0);
    }
#pragma unroll
    for (int sn = 0; sn < 4; sn++) {
#pragma unroll
        for (int rr = 0; rr < 4; rr++) {
            const int t = 16 * wv + 4 * q4 + rr;
            const int s = 16 * sn + l15;
            scb[t][s] = __float2bfloat16((s <= t) ? sc4[sn][rr] : 0.f);
        }
    }
    __syncthreads();   // scb ready

    // Fin = Sc·V : 64x32, K=64 (4 MFMAs/wave), stored in C-layout bf16
    f32x4 fin[2] = {(f32x4){0.f,0.f,0.f,0.f}, (f32x4){0.f,0.f,0.f,0.f}};
#pragma unroll
    for (int kb = 0; kb < 2; kb++) {
        short8 ap8 = *(const short8*)(&scb[16 * wv + l15][kb * 32 + q4 * 8]);
#pragma unroll
        for (int rn = 0; rn < 2; rn++) {
            short8 bv8 = *(const short8*)(&vT[16 * rn + l15][kb * 32 + q4 * 8]);
            fin[rn] = __builtin_amdgcn_mfma_f32_16x16x32_bf16(ap8, bv8, fin[rn], 0, 0, 0);
        }
    }
    {
        bf8pack pf;
#pragma unroll
        for (int rr = 0; rr < 4; rr++) {
            pf.h[rr]     = __float2bfloat16(fin[0][rr]);
            pf.h[4 + rr] = __float2bfloat16(fin[1][rr]);
        }
        *(short8*)(Fin + ((size_t)(ch * 4 + wv) * 64 + lane) * 8) = pf.v;
    }
}

// ---------------------------------------------------------------------------
// K2 (B1): per-superchunk scan, 4x parallel over element-quarters.
// Element-wise: agnostic to the S^T element convention. Materializes the
// exclusive per-chunk prefix Wlocal[ch], decay product Ap[ch], and the
// superchunk totals Wtotal/Atot consumed by phaseC's inline super-scan.
// ---------------------------------------------------------------------------
__global__ __launch_bounds__(64) void phaseB1_kernel(
    const float* __restrict__ Schunk, const float* __restrict__ Pchunk,
    float* __restrict__ Wtotal, float* __restrict__ Atot,
    float* __restrict__ Wlocal, float* __restrict__ Ap)
{
    const int sc   = blockIdx.x >> 2;
    const int part = blockIdx.x & 3;
    const int tid  = threadIdx.x;
    const int e4   = part * 256 + tid * 4;
    const bool w0  = (part == 0) && (tid == 0);
    float4 w = make_float4(0.f, 0.f, 0.f, 0.f);
    float  a = 1.f;
#pragma unroll
    for (int c = 0; c < SCH; c++) {
        const int ch = sc * SCH + c;
        *(float4*)(Wlocal + (size_t)ch * 1024 + e4) = w;   // exclusive prefix
        if (w0) Ap[ch] = a;
        const float p = Pchunk[ch];
        float4 s = *(const float4*)(Schunk + (size_t)ch * 1024 + e4);
        w.x = p * w.x + s.x;  w.y = p * w.y + s.y;
        w.z = p * w.z + s.z;  w.w = p * w.w + s.w;
        a *= p;
    }
    *(float4*)(Wtotal + (size_t)sc * 1024 + e4) = w;
    if (w0) Atot[sc] = a;
}

// ---------------------------------------------------------------------------
// K3 (phase C): inline super-scan + scan-free local state + epilogue.
// Super-scan: w = Atot[s]*w + Wtotal[s][e] for s < scid. Loop-carried dep is
// one FMA (4 cyc); load addresses are scan-INDEPENDENT, so unroll-8 lets the
// L2-hot loads pipeline (this is what round-0's serial version lacked).
// Wo fragments packed per-wave from the L2-hot 6.6 KB Wo; bo read as direct
// float4 (mm0 is 4-aligned and <= 48, always in-bounds).
// Epilogue computes mfma(Wo_frag, fast_frag): lane holds 4 CONTIGUOUS output
// columns (mm = 16c + 4q4 + rr) of one row -> float4 global stores.
// ---------------------------------------------------------------------------
__global__ __launch_bounds__(256) void phaseC_kernel(
    const __hip_bfloat16* __restrict__ Qtil,
    const __hip_bfloat16* __restrict__ Fin,
    const float* __restrict__ Wlocal, const float* __restrict__ Ap,
    const float* __restrict__ Wtotal, const float* __restrict__ Atot,
    const float* __restrict__ Wo, const float* __restrict__ bo,
    float* __restrict__ out)
{
    __shared__ __hip_bfloat16 WstT[32][40];     // Wst^T, bf16
    __shared__ __hip_bfloat16 fastB[CHUNK][40]; // fast_out, bf16 (frag source)

    const int tid  = threadIdx.x;
    const int wv   = tid >> 6;
    const int lane = tid & 63;
    const int l15  = lane & 15;
    const int q4   = lane >> 4;
    const int ch   = blockIdx.x;
    const int t0   = ch * CHUNK;
    const int scid = ch / SCH;

    // Wo fragment pack (registers; identical RNE cvt to the old prepB path)
    short8 aWo[4];
#pragma unroll
    for (int c = 0; c < 4; c++) {
        const int mm = 16 * c + l15;
        bf8pack aw;
        if (mm < MDIM) {
            const float4 w0 = *(const float4*)(Wo + (size_t)mm * 32 + q4 * 8);
            const float4 w1 = *(const float4*)(Wo + (size_t)mm * 32 + q4 * 8 + 4);
            aw.h[0] = __float2bfloat16(w0.x); aw.h[1] = __float2bfloat16(w0.y);
            aw.h[2] = __float2bfloat16(w0.z); aw.h[3] = __float2bfloat16(w0.w);
            aw.h[4] = __float2bfloat16(w1.x); aw.h[5] = __float2bfloat16(w1.y);
            aw.h[6] = __float2bfloat16(w1.z); aw.h[7] = __float2bfloat16(w1.w);
        } else {
#pragma unroll
            for (int j = 0; j < 8; j++) aw.h[j] = __float2bfloat16(0.f);
        }
        aWo[c] = aw.v;
    }

    // carried state: inline super-scan (bit-identical FLOP order to old B2)
    {
        const int e4 = tid * 4;
        float4 wsup = make_float4(0.f, 0.f, 0.f, 0.f);
#pragma unroll 8
        for (int s = 0; s < scid; ++s) {
            const float p = Atot[s];
            const float4 t = *(const float4*)(Wtotal + (size_t)s * 1024 + e4);
            wsup.x = p * wsup.x + t.x;  wsup.y = p * wsup.y + t.y;
            wsup.z = p * wsup.z + t.z;  wsup.w = p * wsup.w + t.w;
        }
        const float apv = Ap[ch];
        const float4 w = *(const float4*)(Wlocal + (size_t)ch * 1024 + e4);
        bf4pack pw;
        pw.h[0] = __float2bfloat16(apv * wsup.x + w.x);
        pw.h[1] = __float2bfloat16(apv * wsup.y + w.y);
        pw.h[2] = __float2bfloat16(apv * wsup.z + w.z);
        pw.h[3] = __float2bfloat16(apv * wsup.w + w.w);
        // e = b*32 + a : b = tid>>3, a = (tid&7)*4
        *(short4_*)(&WstT[tid >> 3][(tid & 7) * 4]) = pw.v;
    }

    // A-fragment: q̃ rows of this wave's t-tile
    const short8 aq = *(const short8*)(Qtil + (size_t)(t0 + 16 * wv + l15) * 32 + q4 * 8);
    // Fin (C-layout) -> C-operand init
    bf8pack pf;
    pf.v = *(const short8*)(Fin + ((size_t)(ch * 4 + wv) * 64 + lane) * 8);
    f32x4 fa[2];
#pragma unroll
    for (int rr = 0; rr < 4; rr++) {
        fa[0][rr] = __bfloat162float(pf.h[rr]);
        fa[1][rr] = __bfloat162float(pf.h[4 + rr]);
    }
    __syncthreads();   // WstT ready

    // fast = Fin + Q̃·Wst
#pragma unroll
    for (int rn = 0; rn < 2; rn++) {
        short8 bw8 = *(const short8*)(&WstT[16 * rn + l15][q4 * 8]);
        fa[rn] = __builtin_amdgcn_mfma_f32_16x16x32_bf16(aq, bw8, fa[rn], 0, 0, 0);
    }
    // fast -> LDS (bf16, fragment source)
#pragma unroll
    for (int rn = 0; rn < 2; rn++)
#pragma unroll
        for (int rr = 0; rr < 4; rr++)
            fastB[16 * wv + 4 * q4 + rr][16 * rn + l15] = __float2bfloat16(fa[rn][rr]);
    __syncthreads();

    // epilogue (operand-swapped): oc = mfma(aWo[c], fast_frag) ->
    // lane holds row t = t0+16wv+l15, cols mm = 16c+4q4+{0..3} -> float4 store
    {
        const short8 bFfast = *(const short8*)(&fastB[16 * wv + l15][q4 * 8]);
        const int mmb = 4 * q4;
#pragma unroll
        for (int c = 0; c < 4; c++) {
            f32x4 oc = __builtin_amdgcn_mfma_f32_16x16x32_bf16(
                aWo[c], bFfast, (f32x4){0.f, 0.f, 0.f, 0.f}, 0, 0, 0);
            const int mm0 = 16 * c + mmb;
            if (mm0 < MDIM) {
                const float4 bb = *(const float4*)(bo + mm0);
                f32x4 ov;
                ov[0] = 2.0f / (1.0f + __expf(-2.0f * (oc[0] + bb.x)));
                ov[1] = 2.0f / (1.0f + __expf(-2.0f * (oc[1] + bb.y)));
                ov[2] = 2.0f / (1.0f + __expf(-2.0f * (oc[2] + bb.z)));
                ov[3] = 2.0f / (1.0f + __expf(-2.0f * (oc[3] + bb.w)));
                *(f32x4*)(out + (size_t)(t0 + 16 * wv + l15) * MDIM + mm0) = ov;
            }
        }
    }
}

// ---------------------------------------------------------------------------
extern "C" void kernel_launch(void* const* d_in, const int* in_sizes, int n_in,
                              void* d_out, int out_size, void* d_ws, size_t ws_size,
                              hipStream_t stream) {
    (void)in_sizes; (void)n_in; (void)out_size; (void)ws_size;
    const float* X   = (const float*)d_in[0];
    const float* lr  = (const float*)d_in[1];
    const float* dec = (const float*)d_in[2];
    const float* Wk  = (const float*)d_in[3];
    const float* bk  = (const float*)d_in[4];
    const float* Wv  = (const float*)d_in[5];
    const float* bv  = (const float*)d_in[6];
    const float* Wq  = (const float*)d_in[7];
    const float* bq  = (const float*)d_in[8];
    const float* Wo  = (const float*)d_in[9];
    const float* bo  = (const float*)d_in[10];
    float* out = (float*)d_out;

    // workspace (floats unless noted):
    // S[NCH*1024] | P[NCH] | Wtotal[NSC*1024] | Atot[NSC]
    // | Wlocal[NCH*1024] | Ap[NCH] | Qtil(bf16 T*32) | Fin(bf16 T*32)
    float* ws    = (float*)d_ws;
    float* S     = ws;
    float* P     = S + (size_t)NCH * 1024;
    float* Wtot  = P + NCH;
    float* Atot  = Wtot + (size_t)NSC * 1024;
    float* Wloc  = Atot + NSC;
    float* Ap    = Wloc + (size_t)NCH * 1024;
    __hip_bfloat16* Qtil = (__hip_bfloat16*)(Ap + NCH);
    __hip_bfloat16* Fin  = Qtil + (size_t)T_STEPS * 32;

    projA_kernel<<<NCH, 256, 0, stream>>>(X, lr, dec, Wk, Wv, Wq, bk, bv, bq,
                                          Qtil, Fin, S, P);
    phaseB1_kernel<<<NSC * 4, 64, 0, stream>>>(S, P, Wtot, Atot, Wloc, Ap);
    phaseC_kernel<<<NCH, 256, 0, stream>>>(Qtil, Fin, Wloc, Ap, Wtot, Atot,
                                           Wo, bo, out);
}

// Round 7
// 148.365 us; speedup vs baseline: 1.1916x; 1.1916x over previous
//
#include <hip/hip_runtime.h>
#include <hip/hip_bf16.h>
#include <math.h>

#define T_STEPS 65536
#define DDIM 256
#define RDIM 32
#define MDIM 52
#define CHUNK 64
#define NCH (T_STEPS / CHUNK)   // 1024 chunks
#define SCH 16                  // chunks per superchunk
#define NSC (NCH / SCH)         // 64 superchunks

typedef short short8 __attribute__((ext_vector_type(8)));   // 8 bf16 (4 VGPRs)
typedef short short4_ __attribute__((ext_vector_type(4)));  // 4 bf16 (2 VGPRs)
typedef float f32x4  __attribute__((ext_vector_type(4)));   // MFMA acc

union bf8pack { short8 v; __hip_bfloat16 h[8]; };
union bf4pack { short4_ v; __hip_bfloat16 h[4]; };

// ---------------------------------------------------------------------------
// K0: pack W = [Wk;Wv;Wq] (96x256) into MFMA B-frag order (bf16), and
// Wo (52x32, zero-padded to 64 rows) into WoFrag.
// frag[(tile*nK + kb)*64 + lane][j] = M[16*tile + (lane&15)][kb*32 + (lane>>4)*8 + j]
// ---------------------------------------------------------------------------
__global__ __launch_bounds__(256) void prepB_kernel(
    const float* __restrict__ Wk, const float* __restrict__ Wv,
    const float* __restrict__ Wq, const float* __restrict__ Wo,
    __hip_bfloat16* __restrict__ Bfrag, __hip_bfloat16* __restrict__ WoFrag)
{
    const int idx = blockIdx.x * 256 + threadIdx.x;
    if (idx < 6 * 8 * 64) {
        const int lane = idx & 63;
        const int kb   = (idx >> 6) & 7;
        const int c    = idx >> 9;
        const int row  = 16 * c + (lane & 15);            // 0..95
        const int k0   = kb * 32 + (lane >> 4) * 8;       // 0..248
        const float* src = (row < 32) ? (Wk + (size_t)row * DDIM)
                         : (row < 64) ? (Wv + (size_t)(row - 32) * DDIM)
                                      : (Wq + (size_t)(row - 64) * DDIM);
        bf8pack p;
#pragma unroll
        for (int j = 0; j < 8; j++) p.h[j] = __float2bfloat16(src[k0 + j]);
        *(short8*)(Bfrag + (size_t)idx * 8) = p.v;
    } else if (idx < 6 * 8 * 64 + 4 * 64) {
        const int i2   = idx - 6 * 8 * 64;                // 0..255
        const int lane = i2 & 63;
        const int c    = i2 >> 6;                         // m-tile 0..3
        const int mm   = 16 * c + (lane & 15);            // 0..63 (pad >=52)
        const int k0   = (lane >> 4) * 8;                 // 0..24
        bf8pack p;
#pragma unroll
        for (int j = 0; j < 8; j++)
            p.h[j] = __float2bfloat16(mm < MDIM ? Wo[(size_t)mm * 32 + k0 + j] : 0.f);
        *(short8*)(WoFrag + (size_t)i2 * 8) = p.v;
    }
}

// ---------------------------------------------------------------------------
// K1: MFMA projections + phase A + intra-chunk attention.
// OCCUPANCY VERSION (round-6 counters: latency-bound, Occ 24%, all pipes idle):
//   - __launch_bounds__(256,8) pins VGPR target to 64 (<=64 => 8 waves/SIMD).
//     X is STREAMED per kb (no 16x float4 hoist — TLP replaces ILP at 8
//     blocks/CU; the hoist was never honored at VGPR 72 anyway).
//   - LDS 28.7KB -> 19.5KB: scb overlays the kR+kT region (scb is only live
//     after the last kR/kT read); one extra barrier fences the overlay.
//   => occupancy 4 -> 8 blocks/CU (LDS 19456*8 = 155.6KB <= 160KB).
// S is stored TRANSPOSED (element e = b*32 + a) -> one float4 store per lane.
// ---------------------------------------------------------------------------
__global__ __launch_bounds__(256, 8) void projA_kernel(
    const float* __restrict__ X,
    const float* __restrict__ lr, const float* __restrict__ decay,
    const float* __restrict__ bk, const float* __restrict__ bv,
    const float* __restrict__ bq,
    const __hip_bfloat16* __restrict__ Bfrag,
    __hip_bfloat16* __restrict__ Qtil, __hip_bfloat16* __restrict__ Fin,
    float* __restrict__ Schunk, float* __restrict__ Pchunk)
{
    // flat LDS, manual layout (elements of bf16):
    //   qR  @ 0     : [64][40]  (2560)   q̃ rows
    //   vT  @ 2560  : [32][72]  (2304)   v^T
    //   kR  @ 4864  : [64][40]  (2560)   k̃ rows      -- dead after scores
    //   kT  @ 7424  : [32][72]  (2304)   k̃^T         -- dead after S-MFMA
    //   scb @ 4864  : [64][72]  (4608)   OVERLAYS kR+kT (4608 <= 4864)
    // total 9728 elems = 19456 B
    __shared__ __hip_bfloat16 smem[9728];
    __hip_bfloat16 (*qR)[40]  = (__hip_bfloat16(*)[40])(smem);
    __hip_bfloat16 (*vT)[72]  = (__hip_bfloat16(*)[72])(smem + 2560);
    __hip_bfloat16 (*kR)[40]  = (__hip_bfloat16(*)[40])(smem + 4864);
    __hip_bfloat16 (*kT)[72]  = (__hip_bfloat16(*)[72])(smem + 7424);
    __hip_bfloat16 (*scb)[72] = (__hip_bfloat16(*)[72])(smem + 4864);

    const int tid  = threadIdx.x;
    const int wv   = tid >> 6;
    const int lane = tid & 63;
    const int l15  = lane & 15;
    const int q4   = lane >> 4;
    const int ch   = blockIdx.x;
    const int t0   = ch * CHUNK;

    // redundant per-wave decay cumprod (no LDS/barrier)
    float bcum = 1.f - decay[t0 + lane];
    const float lcum = lr[t0 + lane];
#pragma unroll
    for (int d = 1; d < 64; d <<= 1) {
        float o = __shfl_up(bcum, d, 64);
        if (lane >= d) bcum *= o;
    }
    const float P = __shfl(bcum, 63, 64);

    // MFMA GEMM: C[64x96] = X_tile[64x256] * W^T — X streamed per kb
    const float* xrow = X + (size_t)(t0 + 16 * wv + l15) * DDIM + q4 * 8;
    f32x4 acc[6];
#pragma unroll
    for (int c = 0; c < 6; c++) acc[c] = (f32x4){0.f, 0.f, 0.f, 0.f};
#pragma unroll
    for (int kb = 0; kb < 8; kb++) {
        const float4 a0 = *(const float4*)(xrow + kb * 32);
        const float4 a1 = *(const float4*)(xrow + kb * 32 + 4);
        bf8pack ap;
        ap.h[0] = __float2bfloat16(a0.x); ap.h[1] = __float2bfloat16(a0.y);
        ap.h[2] = __float2bfloat16(a0.z); ap.h[3] = __float2bfloat16(a0.w);
        ap.h[4] = __float2bfloat16(a1.x); ap.h[5] = __float2bfloat16(a1.y);
        ap.h[6] = __float2bfloat16(a1.z); ap.h[7] = __float2bfloat16(a1.w);
#pragma unroll
        for (int c = 0; c < 6; c++) {
            short8 bf = *(const short8*)(Bfrag + ((size_t)(c * 8 + kb) * 64 + lane) * 8);
            acc[c] = __builtin_amdgcn_mfma_f32_16x16x32_bf16(ap.v, bf, acc[c], 0, 0, 0);
        }
    }

    // per-row scales for this lane's 4 accumulator rows (sloc = 16wv+4q4+r)
    float bbr[4], llr[4];
#pragma unroll
    for (int r = 0; r < 4; r++) {
        const int sloc = 16 * wv + 4 * q4 + r;
        bbr[r] = __shfl(bcum, sloc, 64);
        llr[r] = __shfl(lcum, sloc, 64);
    }

    // scatter accumulators into bf16 LDS tiles (bias inline, L1-hot);
    // kT/vT rows packed as b64
    const int sbase = 16 * wv + 4 * q4;
#pragma unroll
    for (int c = 0; c < 6; c++) {
        const int colg = 16 * c + l15;
        const float bias = (colg < 32) ? bk[colg]
                         : (colg < 64) ? bv[colg - 32] : bq[colg - 64];
        if (c < 2) {
            bf4pack pk;
#pragma unroll
            for (int r = 0; r < 4; r++) {
                __hip_bfloat16 h = __float2bfloat16((acc[c][r] + bias) * (llr[r] / bbr[r]));
                kR[sbase + r][colg] = h;
                pk.h[r] = h;
            }
            *(short4_*)(&kT[colg][sbase]) = pk.v;
        } else if (c < 4) {
            bf4pack pv;
#pragma unroll
            for (int r = 0; r < 4; r++)
                pv.h[r] = __float2bfloat16(acc[c][r] + bias);
            *(short4_*)(&vT[colg - 32][sbase]) = pv.v;
        } else {
#pragma unroll
            for (int r = 0; r < 4; r++)
                qR[sbase + r][colg - 64] = __float2bfloat16((acc[c][r] + bias) * bbr[r]);
        }
    }
    __syncthreads();                    // (1) tiles ready

    // coalesced Qtil plane write
    {
        const int s = tid >> 2, g = (tid & 3) * 8;
        *(short8*)(Qtil + (size_t)(t0 + s) * 32 + g) = *(const short8*)(&qR[s][g]);
    }

    // S^T store: element e = b*32 + a (a = k-idx, b = v-idx), rr fastest
    {
        const int am = wv & 1, bn = wv >> 1;
        f32x4 sacc = (f32x4){0.f, 0.f, 0.f, 0.f};
#pragma unroll
        for (int k2 = 0; k2 < 2; k2++) {
            short8 aF = *(const short8*)(&kT[16 * am + l15][k2 * 32 + q4 * 8]);
            short8 bF = *(const short8*)(&vT[16 * bn + l15][k2 * 32 + q4 * 8]);
            sacc = __builtin_amdgcn_mfma_f32_16x16x32_bf16(aF, bF, sacc, 0, 0, 0);
        }
        f32x4 sv;
#pragma unroll
        for (int rr = 0; rr < 4; rr++) sv[rr] = P * sacc[rr];
        *(f32x4*)(Schunk + (size_t)ch * 1024
                  + (16 * bn + l15) * 32 + 16 * am + 4 * q4) = sv;
    }
    if (tid == 0) Pchunk[ch] = P;

    // scores: Q̃ K̃^T (4 MFMAs/wave) — LAST reads of kR/kT region
    const short8 aq = *(const short8*)(&qR[16 * wv + l15][q4 * 8]);
    f32x4 sc4[4];
#pragma unroll
    for (int sn = 0; sn < 4; sn++) {
        short8 bk8 = *(const short8*)(&kR[16 * sn + l15][q4 * 8]);
        sc4[sn] = __builtin_amdgcn_mfma_f32_16x16x32_bf16(
            aq, bk8, (f32x4){0.f, 0.f, 0.f, 0.f}, 0, 0, 0);
    }
    __syncthreads();   // (2) all kR/kT reads done — overlay is now safe

    // masked scores -> scb (overlays kR+kT memory)
#pragma unroll
    for (int sn = 0; sn < 4; sn++) {
#pragma unroll
        for (int rr = 0; rr < 4; rr++) {
            const int t = 16 * wv + 4 * q4 + rr;
            const int s = 16 * sn + l15;
            scb[t][s] = __float2bfloat16((s <= t) ? sc4[sn][rr] : 0.f);
        }
    }
    __syncthreads();   // (3) scb ready

    // Fin = Sc·V : 64x32, K=64 (4 MFMAs/wave), stored in C-layout bf16
    f32x4 fin[2] = {(f32x4){0.f,0.f,0.f,0.f}, (f32x4){0.f,0.f,0.f,0.f}};
#pragma unroll
    for (int kb = 0; kb < 2; kb++) {
        short8 ap8 = *(const short8*)(&scb[16 * wv + l15][kb * 32 + q4 * 8]);
#pragma unroll
        for (int rn = 0; rn < 2; rn++) {
            short8 bv8 = *(const short8*)(&vT[16 * rn + l15][kb * 32 + q4 * 8]);
            fin[rn] = __builtin_amdgcn_mfma_f32_16x16x32_bf16(ap8, bv8, fin[rn], 0, 0, 0);
        }
    }
    {
        bf8pack pf;
#pragma unroll
        for (int rr = 0; rr < 4; rr++) {
            pf.h[rr]     = __float2bfloat16(fin[0][rr]);
            pf.h[4 + rr] = __float2bfloat16(fin[1][rr]);
        }
        *(short8*)(Fin + ((size_t)(ch * 4 + wv) * 64 + lane) * 8) = pf.v;
    }
}

// ---------------------------------------------------------------------------
// K2 (B1): per-superchunk scan, 4x parallel over element-quarters.
// Materializes exclusive per-chunk prefix Wlocal[ch] and decay product Ap[ch].
// ---------------------------------------------------------------------------
__global__ __launch_bounds__(64) void phaseB1_kernel(
    const float* __restrict__ Schunk, const float* __restrict__ Pchunk,
    float* __restrict__ Wtotal, float* __restrict__ Atot,
    float* __restrict__ Wlocal, float* __restrict__ Ap)
{
    const int sc   = blockIdx.x >> 2;
    const int part = blockIdx.x & 3;
    const int tid  = threadIdx.x;
    const int e4   = part * 256 + tid * 4;
    const bool w0  = (part == 0) && (tid == 0);
    float4 w = make_float4(0.f, 0.f, 0.f, 0.f);
    float  a = 1.f;
#pragma unroll
    for (int c = 0; c < SCH; c++) {
        const int ch = sc * SCH + c;
        *(float4*)(Wlocal + (size_t)ch * 1024 + e4) = w;   // exclusive prefix
        if (w0) Ap[ch] = a;
        const float p = Pchunk[ch];
        float4 s = *(const float4*)(Schunk + (size_t)ch * 1024 + e4);
        w.x = p * w.x + s.x;  w.y = p * w.y + s.y;
        w.z = p * w.z + s.z;  w.w = p * w.w + s.w;
        a *= p;
    }
    *(float4*)(Wtotal + (size_t)sc * 1024 + e4) = w;
    if (w0) Atot[sc] = a;
}

// ---------------------------------------------------------------------------
// K3 (B2): exclusive prefix over the 64 superchunks. 16 blocks x 64 threads,
// compile-time 64-iter full unroll so loads are hoisted ahead of the chain.
// ---------------------------------------------------------------------------
__global__ __launch_bounds__(64) void phaseB2_kernel(
    const float* __restrict__ Wtotal, const float* __restrict__ Atot,
    float* __restrict__ Wsuper)
{
    const int e = blockIdx.x * 64 + threadIdx.x;    // 0..1023
    float w = 0.f;
#pragma unroll
    for (int s = 0; s < NSC; s++) {
        Wsuper[(size_t)s * 1024 + e] = w;           // exclusive
        w = Atot[s] * w + Wtotal[(size_t)s * 1024 + e];
    }
}

// ---------------------------------------------------------------------------
// K4 (phase C): scan-free carried state + swapped-operand epilogue.
// Wst = Ap[ch]*Wsuper[scid] + Wlocal[ch] (two coalesced float4 loads).
// Epilogue computes mfma(Wo_frag, fast_frag): lane holds 4 CONTIGUOUS output
// columns (mm = 16c + 4q4 + rr) of one row -> float4 global stores.
// ---------------------------------------------------------------------------
__global__ __launch_bounds__(256) void phaseC_kernel(
    const __hip_bfloat16* __restrict__ Qtil,
    const __hip_bfloat16* __restrict__ Fin,
    const float* __restrict__ Wlocal, const float* __restrict__ Ap,
    const float* __restrict__ Wsuper,
    const __hip_bfloat16* __restrict__ WoFrag, const float* __restrict__ bo,
    float* __restrict__ out)
{
    __shared__ __hip_bfloat16 WstT[32][40];     // Wst^T, bf16
    __shared__ __hip_bfloat16 fastB[CHUNK][40]; // fast_out, bf16 (frag source)
    __shared__ float bosS[64];                  // bo zero-padded

    const int tid  = threadIdx.x;
    const int wv   = tid >> 6;
    const int lane = tid & 63;
    const int l15  = lane & 15;
    const int q4   = lane >> 4;
    const int ch   = blockIdx.x;
    const int t0   = ch * CHUNK;
    const int scid = ch / SCH;

    // carried state: 2 vector loads + 1 uniform scalar (no scans)
    {
        const int e4 = tid * 4;
        const float apv = Ap[ch];
        float4 wu = *(const float4*)(Wsuper + (size_t)scid * 1024 + e4);
        float4 w  = *(const float4*)(Wlocal + (size_t)ch   * 1024 + e4);
        bf4pack pw;
        pw.h[0] = __float2bfloat16(apv * wu.x + w.x);
        pw.h[1] = __float2bfloat16(apv * wu.y + w.y);
        pw.h[2] = __float2bfloat16(apv * wu.z + w.z);
        pw.h[3] = __float2bfloat16(apv * wu.w + w.w);
        // e = b*32 + a : b = tid>>3, a = (tid&7)*4
        *(short4_*)(&WstT[tid >> 3][(tid & 7) * 4]) = pw.v;
    }
    if (tid < 64) bosS[tid] = (tid < MDIM) ? bo[tid] : 0.f;

    // A-fragment: q̃ rows of this wave's t-tile
    const short8 aq = *(const short8*)(Qtil + (size_t)(t0 + 16 * wv + l15) * 32 + q4 * 8);
    // Fin (C-layout) -> C-operand init
    bf8pack pf;
    pf.v = *(const short8*)(Fin + ((size_t)(ch * 4 + wv) * 64 + lane) * 8);
    f32x4 fa[2];
#pragma unroll
    for (int rr = 0; rr < 4; rr++) {
        fa[0][rr] = __bfloat162float(pf.h[rr]);
        fa[1][rr] = __bfloat162float(pf.h[4 + rr]);
    }
    __syncthreads();   // WstT ready

    // fast = Fin + Q̃·Wst
#pragma unroll
    for (int rn = 0; rn < 2; rn++) {
        short8 bw8 = *(const short8*)(&WstT[16 * rn + l15][q4 * 8]);
        fa[rn] = __builtin_amdgcn_mfma_f32_16x16x32_bf16(aq, bw8, fa[rn], 0, 0, 0);
    }
    // fast -> LDS (bf16, fragment source)
#pragma unroll
    for (int rn = 0; rn < 2; rn++)
#pragma unroll
        for (int rr = 0; rr < 4; rr++)
            fastB[16 * wv + 4 * q4 + rr][16 * rn + l15] = __float2bfloat16(fa[rn][rr]);
    __syncthreads();

    // epilogue (operand-swapped): oc = mfma(WoF[c], fast_frag) ->
    // lane holds row t = t0+16wv+l15, cols mm = 16c+4q4+{0..3} -> float4 store
    {
        const short8 bFfast = *(const short8*)(&fastB[16 * wv + l15][q4 * 8]);
        const int mmb = 4 * q4;
#pragma unroll
        for (int c = 0; c < 4; c++) {
            short8 aWo = *(const short8*)(WoFrag + ((size_t)(c * 64) + lane) * 8);
            f32x4 oc = __builtin_amdgcn_mfma_f32_16x16x32_bf16(
                aWo, bFfast, (f32x4){0.f, 0.f, 0.f, 0.f}, 0, 0, 0);
            const int mm0 = 16 * c + mmb;
            if (mm0 < MDIM) {
                f32x4 ov;
#pragma unroll
                for (int rr = 0; rr < 4; rr++)
                    ov[rr] = 2.0f / (1.0f + __expf(-2.0f * (oc[rr] + bosS[mm0 + rr])));
                *(f32x4*)(out + (size_t)(t0 + 16 * wv + l15) * MDIM + mm0) = ov;
            }
        }
    }
}

// ---------------------------------------------------------------------------
extern "C" void kernel_launch(void* const* d_in, const int* in_sizes, int n_in,
                              void* d_out, int out_size, void* d_ws, size_t ws_size,
                              hipStream_t stream) {
    (void)in_sizes; (void)n_in; (void)out_size; (void)ws_size;
    const float* X   = (const float*)d_in[0];
    const float* lr  = (const float*)d_in[1];
    const float* dec = (const float*)d_in[2];
    const float* Wk  = (const float*)d_in[3];
    const float* bk  = (const float*)d_in[4];
    const float* Wv  = (const float*)d_in[5];
    const float* bv  = (const float*)d_in[6];
    const float* Wq  = (const float*)d_in[7];
    const float* bq  = (const float*)d_in[8];
    const float* Wo  = (const float*)d_in[9];
    const float* bo  = (const float*)d_in[10];
    float* out = (float*)d_out;

    // workspace (floats unless noted):
    // S[NCH*1024] | P[NCH] | Wtotal[NSC*1024] | Atot[NSC]
    // | Wlocal[NCH*1024] | Ap[NCH] | Wsuper[NSC*1024]
    // | Qtil(bf16 T*32) | Fin(bf16 T*32) | Bfrag | WoFrag
    float* ws    = (float*)d_ws;
    float* S     = ws;
    float* P     = S + (size_t)NCH * 1024;
    float* Wtot  = P + NCH;
    float* Atot  = Wtot + (size_t)NSC * 1024;
    float* Wloc  = Atot + NSC;
    float* Ap    = Wloc + (size_t)NCH * 1024;
    float* Wsup  = Ap + NCH;
    __hip_bfloat16* Qtil   = (__hip_bfloat16*)(Wsup + (size_t)NSC * 1024);
    __hip_bfloat16* Fin    = Qtil + (size_t)T_STEPS * 32;
    __hip_bfloat16* Bfrag  = Fin + (size_t)T_STEPS * 32;
    __hip_bfloat16* WoFrag = Bfrag + (size_t)96 * 256;

    prepB_kernel<<<13, 256, 0, stream>>>(Wk, Wv, Wq, Wo, Bfrag, WoFrag);
    projA_kernel<<<NCH, 256, 0, stream>>>(X, lr, dec, bk, bv, bq, Bfrag,
                                          Qtil, Fin, S, P);
    phaseB1_kernel<<<NSC * 4, 64, 0, stream>>>(S, P, Wtot, Atot, Wloc, Ap);
    phaseB2_kernel<<<16, 64, 0, stream>>>(Wtot, Atot, Wsup);
    phaseC_kernel<<<NCH, 256, 0, stream>>>(Qtil, Fin, Wloc, Ap, Wsup,
                                           WoFrag, bo, out);
}

// Round 8
// 141.436 us; speedup vs baseline: 1.2500x; 1.0490x over previous
//
#include <hip/hip_runtime.h>
#include <hip/hip_bf16.h>
#include <math.h>

#define T_STEPS 65536
#define DDIM 256
#define RDIM 32
#define MDIM 52
#define CHUNK 64
#define NCH (T_STEPS / CHUNK)   // 1024 chunks
#define SCH 16                  // chunks per superchunk
#define NSC (NCH / SCH)         // 64 superchunks

typedef short short8 __attribute__((ext_vector_type(8)));   // 8 bf16 (4 VGPRs)
typedef short short4_ __attribute__((ext_vector_type(4)));  // 4 bf16 (2 VGPRs)
typedef float f32x4  __attribute__((ext_vector_type(4)));   // MFMA acc

union bf8pack { short8 v; __hip_bfloat16 h[8]; };
union bf4pack { short4_ v; __hip_bfloat16 h[4]; };

// ---------------------------------------------------------------------------
// K0: pack W = [Wk;Wv;Wq] (96x256) into MFMA B-frag order (bf16), and
// Wo (52x32, zero-padded to 64 rows) into WoFrag.
// frag[(tile*nK + kb)*64 + lane][j] = M[16*tile + (lane&15)][kb*32 + (lane>>4)*8 + j]
// ---------------------------------------------------------------------------
__global__ __launch_bounds__(256) void prepB_kernel(
    const float* __restrict__ Wk, const float* __restrict__ Wv,
    const float* __restrict__ Wq, const float* __restrict__ Wo,
    __hip_bfloat16* __restrict__ Bfrag, __hip_bfloat16* __restrict__ WoFrag)
{
    const int idx = blockIdx.x * 256 + threadIdx.x;
    if (idx < 6 * 8 * 64) {
        const int lane = idx & 63;
        const int kb   = (idx >> 6) & 7;
        const int c    = idx >> 9;
        const int row  = 16 * c + (lane & 15);            // 0..95
        const int k0   = kb * 32 + (lane >> 4) * 8;       // 0..248
        const float* src = (row < 32) ? (Wk + (size_t)row * DDIM)
                         : (row < 64) ? (Wv + (size_t)(row - 32) * DDIM)
                                      : (Wq + (size_t)(row - 64) * DDIM);
        bf8pack p;
#pragma unroll
        for (int j = 0; j < 8; j++) p.h[j] = __float2bfloat16(src[k0 + j]);
        *(short8*)(Bfrag + (size_t)idx * 8) = p.v;
    } else if (idx < 6 * 8 * 64 + 4 * 64) {
        const int i2   = idx - 6 * 8 * 64;                // 0..255
        const int lane = i2 & 63;
        const int c    = i2 >> 6;                         // m-tile 0..3
        const int mm   = 16 * c + (lane & 15);            // 0..63 (pad >=52)
        const int k0   = (lane >> 4) * 8;                 // 0..24
        bf8pack p;
#pragma unroll
        for (int j = 0; j < 8; j++)
            p.h[j] = __float2bfloat16(mm < MDIM ? Wo[(size_t)mm * 32 + k0 + j] : 0.f);
        *(short8*)(WoFrag + (size_t)i2 * 8) = p.v;
    }
}

// ---------------------------------------------------------------------------
// K1: MFMA projections + phase A + intra-chunk attention. 2 barriers only.
// __launch_bounds__(256,4): grid is exactly 4 blocks/CU, so <=128 VGPR is
// free headroom for the 16 hoisted X float4 loads. Bias values for the
// scatter are prefetched alongside the X loads so their L1 latency hides
// under the MFMA loop instead of stalling the accumulator scatter.
// S is stored TRANSPOSED (element e = b*32 + a) so the MFMA reg axis is
// memory-fastest -> one float4 store per lane.
// ---------------------------------------------------------------------------
__global__ __launch_bounds__(256, 4) void projA_kernel(
    const float* __restrict__ X,
    const float* __restrict__ lr, const float* __restrict__ decay,
    const float* __restrict__ bk, const float* __restrict__ bv,
    const float* __restrict__ bq,
    const __hip_bfloat16* __restrict__ Bfrag,
    __hip_bfloat16* __restrict__ Qtil, __hip_bfloat16* __restrict__ Fin,
    float* __restrict__ Schunk, float* __restrict__ Pchunk)
{
    __shared__ __hip_bfloat16 kR[CHUNK][40];  // k̃ rows (scores B-frag)
    __shared__ __hip_bfloat16 qR[CHUNK][40];  // q̃ rows (A-frag + plane copy)
    __shared__ __hip_bfloat16 kT[32][72];     // k̃^T (S-MFMA A-frag)
    __shared__ __hip_bfloat16 vT[32][72];     // v^T  (S-MFMA + PV B-frag)
    __shared__ __hip_bfloat16 scb[CHUNK][72]; // masked scores

    const int tid  = threadIdx.x;
    const int wv   = tid >> 6;
    const int lane = tid & 63;
    const int l15  = lane & 15;
    const int q4   = lane >> 4;
    const int ch   = blockIdx.x;
    const int t0   = ch * CHUNK;

    // redundant per-wave decay cumprod (overlaps X-load latency; no LDS/barrier)
    float bcum = 1.f - decay[t0 + lane];
    const float lcum = lr[t0 + lane];
#pragma unroll
    for (int d = 1; d < 64; d <<= 1) {
        float o = __shfl_up(bcum, d, 64);
        if (lane >= d) bcum *= o;
    }
    const float P = __shfl(bcum, 63, 64);

    // MFMA GEMM: C[64x96] = X_tile[64x256] * W^T  — all 16 X loads hoisted
    const float* xrow = X + (size_t)(t0 + 16 * wv + l15) * DDIM + q4 * 8;
    float4 xa[16];
#pragma unroll
    for (int kb = 0; kb < 8; kb++) {
        xa[2 * kb]     = *(const float4*)(xrow + kb * 32);
        xa[2 * kb + 1] = *(const float4*)(xrow + kb * 32 + 4);
    }
    // bias prefetch (L1-hot; issued early, consumed after the MFMA loop)
    float biasr[6];
#pragma unroll
    for (int c = 0; c < 6; c++) {
        const int colg = 16 * c + l15;
        biasr[c] = (colg < 32) ? bk[colg]
                 : (colg < 64) ? bv[colg - 32] : bq[colg - 64];
    }
    f32x4 acc[6];
#pragma unroll
    for (int c = 0; c < 6; c++) acc[c] = (f32x4){0.f, 0.f, 0.f, 0.f};
#pragma unroll
    for (int kb = 0; kb < 8; kb++) {
        const float4 a0 = xa[2 * kb], a1 = xa[2 * kb + 1];
        bf8pack ap;
        ap.h[0] = __float2bfloat16(a0.x); ap.h[1] = __float2bfloat16(a0.y);
        ap.h[2] = __float2bfloat16(a0.z); ap.h[3] = __float2bfloat16(a0.w);
        ap.h[4] = __float2bfloat16(a1.x); ap.h[5] = __float2bfloat16(a1.y);
        ap.h[6] = __float2bfloat16(a1.z); ap.h[7] = __float2bfloat16(a1.w);
#pragma unroll
        for (int c = 0; c < 6; c++) {
            short8 bf = *(const short8*)(Bfrag + ((size_t)(c * 8 + kb) * 64 + lane) * 8);
            acc[c] = __builtin_amdgcn_mfma_f32_16x16x32_bf16(ap.v, bf, acc[c], 0, 0, 0);
        }
    }

    // per-row scales for this lane's 4 accumulator rows (sloc = 16wv+4q4+r)
    float bbr[4], llr[4];
#pragma unroll
    for (int r = 0; r < 4; r++) {
        const int sloc = 16 * wv + 4 * q4 + r;
        bbr[r] = __shfl(bcum, sloc, 64);
        llr[r] = __shfl(lcum, sloc, 64);
    }

    // scatter accumulators into bf16 LDS tiles; kT/vT rows packed as b64
    const int sbase = 16 * wv + 4 * q4;
#pragma unroll
    for (int c = 0; c < 6; c++) {
        const int colg = 16 * c + l15;
        const float bias = biasr[c];
        if (c < 2) {
            bf4pack pk;
#pragma unroll
            for (int r = 0; r < 4; r++) {
                __hip_bfloat16 h = __float2bfloat16((acc[c][r] + bias) * (llr[r] / bbr[r]));
                kR[sbase + r][colg] = h;
                pk.h[r] = h;
            }
            *(short4_*)(&kT[colg][sbase]) = pk.v;
        } else if (c < 4) {
            bf4pack pv;
#pragma unroll
            for (int r = 0; r < 4; r++)
                pv.h[r] = __float2bfloat16(acc[c][r] + bias);
            *(short4_*)(&vT[colg - 32][sbase]) = pv.v;
        } else {
#pragma unroll
            for (int r = 0; r < 4; r++)
                qR[sbase + r][colg - 64] = __float2bfloat16((acc[c][r] + bias) * bbr[r]);
        }
    }
    __syncthreads();                    // tiles ready

    // coalesced Qtil plane write
    {
        const int s = tid >> 2, g = (tid & 3) * 8;
        *(short8*)(Qtil + (size_t)(t0 + s) * 32 + g) = *(const short8*)(&qR[s][g]);
    }

    // S^T store: element e = b*32 + a (a = k-idx, b = v-idx), rr fastest
    {
        const int am = wv & 1, bn = wv >> 1;
        f32x4 sacc = (f32x4){0.f, 0.f, 0.f, 0.f};
#pragma unroll
        for (int k2 = 0; k2 < 2; k2++) {
            short8 aF = *(const short8*)(&kT[16 * am + l15][k2 * 32 + q4 * 8]);
            short8 bF = *(const short8*)(&vT[16 * bn + l15][k2 * 32 + q4 * 8]);
            sacc = __builtin_amdgcn_mfma_f32_16x16x32_bf16(aF, bF, sacc, 0, 0, 0);
        }
        // lane holds a = 16am+4q4+rr (reg axis), b = 16bn+l15 (col axis)
        f32x4 sv;
#pragma unroll
        for (int rr = 0; rr < 4; rr++) sv[rr] = P * sacc[rr];
        *(f32x4*)(Schunk + (size_t)ch * 1024
                  + (16 * bn + l15) * 32 + 16 * am + 4 * q4) = sv;
    }
    if (tid == 0) Pchunk[ch] = P;

    // scores: Q̃ K̃^T (4 MFMAs/wave), mask s<=t, bf16 -> scb
    const short8 aq = *(const short8*)(&qR[16 * wv + l15][q4 * 8]);
    f32x4 sc4[4];
#pragma unroll
    for (int sn = 0; sn < 4; sn++) {
        short8 bk8 = *(const short8*)(&kR[16 * sn + l15][q4 * 8]);
        sc4[sn] = __builtin_amdgcn_mfma_f32_16x16x32_bf16(
            aq, bk8, (f32x4){0.f, 0.f, 0.f, 0.f}, 0, 0, 0);
    }
#pragma unroll
    for (int sn = 0; sn < 4; sn++) {
#pragma unroll
        for (int rr = 0; rr < 4; rr++) {
            const int t = 16 * wv + 4 * q4 + rr;
            const int s = 16 * sn + l15;
            scb[t][s] = __float2bfloat16((s <= t) ? sc4[sn][rr] : 0.f);
        }
    }
    __syncthreads();   // scb ready

    // Fin = Sc·V : 64x32, K=64 (4 MFMAs/wave), stored in C-layout bf16
    f32x4 fin[2] = {(f32x4){0.f,0.f,0.f,0.f}, (f32x4){0.f,0.f,0.f,0.f}};
#pragma unroll
    for (int kb = 0; kb < 2; kb++) {
        short8 ap8 = *(const short8*)(&scb[16 * wv + l15][kb * 32 + q4 * 8]);
#pragma unroll
        for (int rn = 0; rn < 2; rn++) {
            short8 bv8 = *(const short8*)(&vT[16 * rn + l15][kb * 32 + q4 * 8]);
            fin[rn] = __builtin_amdgcn_mfma_f32_16x16x32_bf16(ap8, bv8, fin[rn], 0, 0, 0);
        }
    }
    {
        bf8pack pf;
#pragma unroll
        for (int rr = 0; rr < 4; rr++) {
            pf.h[rr]     = __float2bfloat16(fin[0][rr]);
            pf.h[4 + rr] = __float2bfloat16(fin[1][rr]);
        }
        *(short8*)(Fin + ((size_t)(ch * 4 + wv) * 64 + lane) * 8) = pf.v;
    }
}

// ---------------------------------------------------------------------------
// K2 (B1): per-superchunk scan, 4x parallel over element-quarters.
// Element-wise: agnostic to the S^T element convention. Also materializes
// the exclusive per-chunk prefix Wlocal[ch] and decay product Ap[ch].
// ---------------------------------------------------------------------------
__global__ __launch_bounds__(64) void phaseB1_kernel(
    const float* __restrict__ Schunk, const float* __restrict__ Pchunk,
    float* __restrict__ Wtotal, float* __restrict__ Atot,
    float* __restrict__ Wlocal, float* __restrict__ Ap)
{
    const int sc   = blockIdx.x >> 2;
    const int part = blockIdx.x & 3;
    const int tid  = threadIdx.x;
    const int e4   = part * 256 + tid * 4;
    const bool w0  = (part == 0) && (tid == 0);
    float4 w = make_float4(0.f, 0.f, 0.f, 0.f);
    float  a = 1.f;
#pragma unroll
    for (int c = 0; c < SCH; c++) {
        const int ch = sc * SCH + c;
        *(float4*)(Wlocal + (size_t)ch * 1024 + e4) = w;   // exclusive prefix
        if (w0) Ap[ch] = a;
        const float p = Pchunk[ch];
        float4 s = *(const float4*)(Schunk + (size_t)ch * 1024 + e4);
        w.x = p * w.x + s.x;  w.y = p * w.y + s.y;
        w.z = p * w.z + s.z;  w.w = p * w.w + s.w;
        a *= p;
    }
    *(float4*)(Wtotal + (size_t)sc * 1024 + e4) = w;
    if (w0) Atot[sc] = a;
}

// ---------------------------------------------------------------------------
// K3 (B2): exclusive prefix over the 64 superchunks. 16 blocks x 64 threads,
// one matrix element per thread (coalesced 256B per wave per iter),
// compile-time 64-iter full unroll so loads are hoisted ahead of the chain.
// ---------------------------------------------------------------------------
__global__ __launch_bounds__(64) void phaseB2_kernel(
    const float* __restrict__ Wtotal, const float* __restrict__ Atot,
    float* __restrict__ Wsuper)
{
    const int e = blockIdx.x * 64 + threadIdx.x;    // 0..1023
    float w = 0.f;
#pragma unroll
    for (int s = 0; s < NSC; s++) {
        Wsuper[(size_t)s * 1024 + e] = w;           // exclusive
        w = Atot[s] * w + Wtotal[(size_t)s * 1024 + e];
    }
}

// ---------------------------------------------------------------------------
// K4 (phase C): scan-free carried state + swapped-operand epilogue.
// Element e = b*32 + a of Wst (S^T convention): thread tid's float4 holds
// b = tid>>3, a = (tid&7)*4 + j  ->  WstT[b][a..a+3] is one b64 row write.
// Epilogue computes mfma(Wo_frag, fast_frag): lane holds 4 CONTIGUOUS
// output columns (mm = 16c + 4q4 + rr) of one row -> float4 global stores.
// ---------------------------------------------------------------------------
__global__ __launch_bounds__(256) void phaseC_kernel(
    const __hip_bfloat16* __restrict__ Qtil,
    const __hip_bfloat16* __restrict__ Fin,
    const float* __restrict__ Wlocal, const float* __restrict__ Ap,
    const float* __restrict__ Wsuper,
    const __hip_bfloat16* __restrict__ WoFrag, const float* __restrict__ bo,
    float* __restrict__ out)
{
    __shared__ __hip_bfloat16 WstT[32][40];     // Wst^T, bf16
    __shared__ __hip_bfloat16 fastB[CHUNK][40]; // fast_out, bf16 (frag source)
    __shared__ float bosS[64];                  // bo zero-padded

    const int tid  = threadIdx.x;
    const int wv   = tid >> 6;
    const int lane = tid & 63;
    const int l15  = lane & 15;
    const int q4   = lane >> 4;
    const int ch   = blockIdx.x;
    const int t0   = ch * CHUNK;
    const int scid = ch / SCH;

    // carried state: 2 vector loads + 1 uniform scalar (no scans)
    {
        const int e4 = tid * 4;
        const float apv = Ap[ch];
        float4 wu = *(const float4*)(Wsuper + (size_t)scid * 1024 + e4);
        float4 w  = *(const float4*)(Wlocal + (size_t)ch   * 1024 + e4);
        bf4pack pw;
        pw.h[0] = __float2bfloat16(apv * wu.x + w.x);
        pw.h[1] = __float2bfloat16(apv * wu.y + w.y);
        pw.h[2] = __float2bfloat16(apv * wu.z + w.z);
        pw.h[3] = __float2bfloat16(apv * wu.w + w.w);
        // e = b*32 + a : b = tid>>3, a = (tid&7)*4
        *(short4_*)(&WstT[tid >> 3][(tid & 7) * 4]) = pw.v;
    }
    if (tid < 64) bosS[tid] = (tid < MDIM) ? bo[tid] : 0.f;

    // A-fragment: q̃ rows of this wave's t-tile
    const short8 aq = *(const short8*)(Qtil + (size_t)(t0 + 16 * wv + l15) * 32 + q4 * 8);
    // Fin (C-layout) -> C-operand init
    bf8pack pf;
    pf.v = *(const short8*)(Fin + ((size_t)(ch * 4 + wv) * 64 + lane) * 8);
    f32x4 fa[2];
#pragma unroll
    for (int rr = 0; rr < 4; rr++) {
        fa[0][rr] = __bfloat162float(pf.h[rr]);
        fa[1][rr] = __bfloat162float(pf.h[4 + rr]);
    }
    __syncthreads();   // WstT ready

    // fast = Fin + Q̃·Wst
#pragma unroll
    for (int rn = 0; rn < 2; rn++) {
        short8 bw8 = *(const short8*)(&WstT[16 * rn + l15][q4 * 8]);
        fa[rn] = __builtin_amdgcn_mfma_f32_16x16x32_bf16(aq, bw8, fa[rn], 0, 0, 0);
    }
    // fast -> LDS (bf16, fragment source)
#pragma unroll
    for (int rn = 0; rn < 2; rn++)
#pragma unroll
        for (int rr = 0; rr < 4; rr++)
            fastB[16 * wv + 4 * q4 + rr][16 * rn + l15] = __float2bfloat16(fa[rn][rr]);
    __syncthreads();

    // epilogue (operand-swapped): oc = mfma(WoF[c], fast_frag) ->
    // lane holds row t = t0+16wv+l15, cols mm = 16c+4q4+{0..3} -> float4 store
    {
        const short8 bFfast = *(const short8*)(&fastB[16 * wv + l15][q4 * 8]);
        const int mmb = 4 * q4;
#pragma unroll
        for (int c = 0; c < 4; c++) {
            short8 aWo = *(const short8*)(WoFrag + ((size_t)(c * 64) + lane) * 8);
            f32x4 oc = __builtin_amdgcn_mfma_f32_16x16x32_bf16(
                aWo, bFfast, (f32x4){0.f, 0.f, 0.f, 0.f}, 0, 0, 0);
            const int mm0 = 16 * c + mmb;
            if (mm0 < MDIM) {
                f32x4 ov;
#pragma unroll
                for (int rr = 0; rr < 4; rr++)
                    ov[rr] = 2.0f / (1.0f + __expf(-2.0f * (oc[rr] + bosS[mm0 + rr])));
                *(f32x4*)(out + (size_t)(t0 + 16 * wv + l15) * MDIM + mm0) = ov;
            }
        }
    }
}

// ---------------------------------------------------------------------------
extern "C" void kernel_launch(void* const* d_in, const int* in_sizes, int n_in,
                              void* d_out, int out_size, void* d_ws, size_t ws_size,
                              hipStream_t stream) {
    (void)in_sizes; (void)n_in; (void)out_size; (void)ws_size;
    const float* X   = (const float*)d_in[0];
    const float* lr  = (const float*)d_in[1];
    const float* dec = (const float*)d_in[2];
    const float* Wk  = (const float*)d_in[3];
    const float* bk  = (const float*)d_in[4];
    const float* Wv  = (const float*)d_in[5];
    const float* bv  = (const float*)d_in[6];
    const float* Wq  = (const float*)d_in[7];
    const float* bq  = (const float*)d_in[8];
    const float* Wo  = (const float*)d_in[9];
    const float* bo  = (const float*)d_in[10];
    float* out = (float*)d_out;

    // workspace (floats unless noted):
    // S[NCH*1024] | P[NCH] | Wtotal[NSC*1024] | Atot[NSC]
    // | Wlocal[NCH*1024] | Ap[NCH] | Wsuper[NSC*1024]
    // | Qtil(bf16 T*32) | Fin(bf16 T*32) | Bfrag | WoFrag
    float* ws    = (float*)d_ws;
    float* S     = ws;
    float* P     = S + (size_t)NCH * 1024;
    float* Wtot  = P + NCH;
    float* Atot  = Wtot + (size_t)NSC * 1024;
    float* Wloc  = Atot + NSC;
    float* Ap    = Wloc + (size_t)NCH * 1024;
    float* Wsup  = Ap + NCH;
    __hip_bfloat16* Qtil   = (__hip_bfloat16*)(Wsup + (size_t)NSC * 1024);
    __hip_bfloat16* Fin    = Qtil + (size_t)T_STEPS * 32;
    __hip_bfloat16* Bfrag  = Fin + (size_t)T_STEPS * 32;
    __hip_bfloat16* WoFrag = Bfrag + (size_t)96 * 256;

    prepB_kernel<<<13, 256, 0, stream>>>(Wk, Wv, Wq, Wo, Bfrag, WoFrag);
    projA_kernel<<<NCH, 256, 0, stream>>>(X, lr, dec, bk, bv, bq, Bfrag,
                                          Qtil, Fin, S, P);
    phaseB1_kernel<<<NSC * 4, 64, 0, stream>>>(S, P, Wtot, Atot, Wloc, Ap);
    phaseB2_kernel<<<16, 64, 0, stream>>>(Wtot, Atot, Wsup);
    phaseC_kernel<<<NCH, 256, 0, stream>>>(Qtil, Fin, Wloc, Ap, Wsup,
                                           WoFrag, bo, out);
}